// Round 1
// baseline (160.648 us; speedup 1.0000x reference)
//
#include <hip/hip_runtime.h>
#include <cstdint>

// CTC batch cost, scaled linear-domain forward algorithm.
// B=256 blocks x 1 wave (64 lanes). Lane i owns extended states {2i, 2i+1};
// a2 track duplicates state 2i+2 (lane63's a2 = state 128, the final blank).
// Cross-lane dependency = one DPP wave_shr:1 per step. Probabilities staged
// global->LDS via global_load_lds dwordx4, double-buffered 24KB chunks,
// counted vmcnt (never drained mid-stream).

constexpr int BB = 256;
constexpr int TT = 1024;
constexpr int CC = 96;
constexpr int LL = 64;
constexpr int CT = 64;                        // rows per chunk
constexpr int NCH = TT / CT;                  // 16 chunks
constexpr int CHUNK_FLOATS = CT * CC;         // 6144
constexpr int CHUNK_BYTES  = CHUNK_FLOATS*4;  // 24576
#define EPSF 1e-7f

__device__ __forceinline__ float wf_shr1_f(float v) {
  // whole-wave shift up by 1 lane; lane 0 receives 0.0f (identity for linear domain)
  int r = __builtin_amdgcn_update_dpp(0, __float_as_int(v), 0x138 /*WAVE_SHR1*/, 0xF, 0xF, false);
  return __int_as_float(r);
}

template <int CTRL>
__device__ __forceinline__ float dpp_max(float v) {
  // invalid source lanes keep old (=v) -> identity for max
  int r = __builtin_amdgcn_update_dpp(__float_as_int(v), __float_as_int(v), CTRL, 0xF, 0xF, false);
  return fmaxf(v, __int_as_float(r));
}

__device__ __forceinline__ void async16(void* lds, const void* g) {
  __builtin_amdgcn_global_load_lds((const __attribute__((address_space(1))) void*)g,
                                   (__attribute__((address_space(3))) void*)lds,
                                   16, 0, 0);
}

__global__ void __launch_bounds__(64, 1)
ctc_fwd(const int* __restrict__ y_true, const float* __restrict__ y_pred,
        float* __restrict__ out) {
  __shared__ alignas(16) float buf[2][CHUNK_FLOATS];
  const int b    = blockIdx.x;
  const int lane = threadIdx.x;

  const int lab  = y_true[b * LL + lane];                 // label for state 2*lane+1
  const int labp = __builtin_amdgcn_update_dpp(-1, lab, 0x138, 0xF, 0xF, false);
  const float mskip = (lane > 0 && lab != labp) ? 1.0f : 0.0f;  // skip s-2 -> s allowed

  const char* src = (const char*)(y_pred + (size_t)b * (TT * CC));

  // prologue: stage chunks 0 and 1
  {
    const char* g0 = src + lane * 16;
#pragma unroll
    for (int j = 0; j < 24; ++j) async16((char*)&buf[0][0] + j * 1024, g0 + j * 1024);
    const char* g1 = src + CHUNK_BYTES + lane * 16;
#pragma unroll
    for (int j = 0; j < 24; ++j) async16((char*)&buf[1][0] + j * 1024, g1 + j * 1024);
  }

  // Seed so that running row 0 as a normal step yields the reference init:
  // a0(lane0)=1 -> na0 = pb, na1 = pl, everything else 0.
  float a0 = (lane == 0) ? 1.0f : 0.0f;
  float a1 = 0.0f;
  float a2 = 0.0f;
  int   scale = 0;   // exact sum of power-of-2 rescale exponents

  for (int c = 0; c < NCH; ++c) {
    if (c < NCH - 1) asm volatile("s_waitcnt vmcnt(24)" ::: "memory"); // chunk c done, c+1 in flight
    else             asm volatile("s_waitcnt vmcnt(0)"  ::: "memory");

    const float* bp = &buf[c & 1][0];
#pragma unroll
    for (int g8 = 0; g8 < 8; ++g8) {
#pragma unroll
      for (int u = 0; u < 8; ++u) {
        const int r = g8 * 8 + u;                       // compile-time -> ds imm offsets
        const float pl  = bp[r * CC + lab] + EPSF;      // label prob (per-lane gather)
        const float pb  = bp[r * CC + (CC - 1)] + EPSF; // blank prob (broadcast)
        const float a1p = wf_shr1_f(a1);                // alpha[2i-1]
        const float na0 = (a0 + a1p) * pb;              // blank state 2i
        float s3 = a1 + a0;
        s3 = fmaf(a1p, mskip, s3);
        const float na1 = s3 * pl;                      // label state 2i+1
        const float na2 = (a2 + a1) * pb;               // state 2i+2 (lane63: state 128)
        a0 = na0; a1 = na1; a2 = na2;
      }
      // exact power-of-2 rescale every 8 steps (decay ~2^-53 between rescales)
      float m = fmaxf(fmaxf(a0, a1), a2);
      m = dpp_max<0x111>(m);   // row_shr:1
      m = dpp_max<0x112>(m);   // row_shr:2
      m = dpp_max<0x114>(m);   // row_shr:4
      m = dpp_max<0x118>(m);   // row_shr:8
      m = dpp_max<0x142>(m);   // row_bcast:15
      m = dpp_max<0x143>(m);   // row_bcast:31  -> lane 63 = wave max
      const int mb = __builtin_amdgcn_readlane(__float_as_int(m), 63);
      const int k  = 227 - ((mb >> 23) & 0xFF);  // bring max to ~2^100
      scale += k;
      a0 = ldexpf(a0, k);
      a1 = ldexpf(a1, k);
      a2 = ldexpf(a2, k);
    }

    // reads of buf[c&1] are all retired (consumed by VALU above) -> safe to overwrite
    if (c + 2 < NCH) {
      const char* g = src + (size_t)(c + 2) * CHUNK_BYTES + lane * 16;
      char* l = (char*)&buf[c & 1][0];
#pragma unroll
      for (int j = 0; j < 24; ++j) async16(l + j * 1024, g + j * 1024);
    }
  }

  if (lane == 63) {
    const float s = a1 + a2;  // alpha[127] + alpha[128] (stored scale)
    // true loss = scale*ln2 - ln(s)
    out[b] = 0.693147180559945f * ((float)scale - log2f(s));
  }
}

extern "C" void kernel_launch(void* const* d_in, const int* in_sizes, int n_in,
                              void* d_out, int out_size, void* d_ws, size_t ws_size,
                              hipStream_t stream) {
  (void)in_sizes; (void)n_in; (void)d_ws; (void)ws_size; (void)out_size;
  const int*   y_true = (const int*)d_in[0];
  const float* y_pred = (const float*)d_in[1];
  float*       out    = (float*)d_out;
  ctc_fwd<<<BB, 64, 0, stream>>>(y_true, y_pred, out);
}

// Round 5
// 152.860 us; speedup vs baseline: 1.0510x; 1.0510x over previous
//
#include <hip/hip_runtime.h>
#include <cstdint>

// CTC batch cost, scaled linear-domain forward algorithm.
// B=256 blocks x 1 wave. Lane i owns extended states {2i, 2i+1}; a2 track
// duplicates state 2i+2 (lane63's a2 = state 128). Cross-lane dep = one DPP
// wave_shr:1 per step. y_pred staged global->LDS via global_load_lds dwordx4,
// double-buffered 24KB chunks, counted vmcnt.
// R2-R5: explicit 8-step-ahead register prefetch of pl/pb (the compiler
// was leaving ~120cy LDS latency exposed per step: 1 wave/CU = no TLP, so
// latency must be hidden by ILP we schedule ourselves). Rescale every 16.
// (R5 = R2 resubmitted after three infra failures; no logic change.)

constexpr int BB = 256;
constexpr int TT = 1024;
constexpr int CC = 96;
constexpr int LL = 64;
constexpr int CT = 64;                        // rows per chunk
constexpr int NCH = TT / CT;                  // 16 chunks
constexpr int CHUNK_FLOATS = CT * CC;         // 6144
constexpr int CHUNK_BYTES  = CHUNK_FLOATS*4;  // 24576
#define EPSF 1e-7f

__device__ __forceinline__ float wf_shr1_f(float v) {
  // whole-wave shift up by 1 lane; lane 0 receives 0.0f (identity here)
  int r = __builtin_amdgcn_update_dpp(0, __float_as_int(v), 0x138 /*WAVE_SHR1*/, 0xF, 0xF, false);
  return __int_as_float(r);
}

template <int CTRL>
__device__ __forceinline__ float dpp_max(float v) {
  int r = __builtin_amdgcn_update_dpp(__float_as_int(v), __float_as_int(v), CTRL, 0xF, 0xF, false);
  return fmaxf(v, __int_as_float(r));
}

__device__ __forceinline__ void async16(void* lds, const void* g) {
  __builtin_amdgcn_global_load_lds((const __attribute__((address_space(1))) void*)g,
                                   (__attribute__((address_space(3))) void*)lds,
                                   16, 0, 0);
}

__global__ void __launch_bounds__(64, 1)
ctc_fwd(const int* __restrict__ y_true, const float* __restrict__ y_pred,
        float* __restrict__ out) {
  __shared__ alignas(16) float buf[2][CHUNK_FLOATS];
  const int b    = blockIdx.x;
  const int lane = threadIdx.x;

  const int lab  = y_true[b * LL + lane];                 // label for state 2*lane+1
  const int labp = __builtin_amdgcn_update_dpp(-1, lab, 0x138, 0xF, 0xF, false);
  const float mskip = (lane > 0 && lab != labp) ? 1.0f : 0.0f;

  const char* src = (const char*)(y_pred + (size_t)b * (TT * CC));

  // prologue: stage chunks 0 and 1
  {
    const char* g0 = src + lane * 16;
#pragma unroll
    for (int j = 0; j < 24; ++j) async16((char*)&buf[0][0] + j * 1024, g0 + j * 1024);
    const char* g1 = src + CHUNK_BYTES + lane * 16;
#pragma unroll
    for (int j = 0; j < 24; ++j) async16((char*)&buf[1][0] + j * 1024, g1 + j * 1024);
  }

  // Seed so that row 0 as a normal step yields the reference init.
  float a0 = (lane == 0) ? 1.0f : 0.0f;
  float a1 = 0.0f;
  float a2 = 0.0f;
  int   scale = 0;   // exact sum of power-of-2 rescale exponents

  for (int c = 0; c < NCH; ++c) {
    if (c < NCH - 1) asm volatile("s_waitcnt vmcnt(24)" ::: "memory"); // chunk c done, c+1 in flight
    else             asm volatile("s_waitcnt vmcnt(0)"  ::: "memory");

    const float* __restrict__ bp = &buf[c & 1][0];

    // register prefetch buffers, statically indexed (stay in VGPRs)
    float pl[2][8], pb[2][8];
#pragma unroll
    for (int u = 0; u < 8; ++u) {
      pl[0][u] = bp[u * CC + lab];
      pb[0][u] = bp[u * CC + (CC - 1)];
    }

#pragma unroll
    for (int g = 0; g < 8; ++g) {
      const int cs = g & 1, ns = cs ^ 1;   // compile-time under full unroll
      if (g < 7) {
        const int base = (g + 1) * 8 * CC;
#pragma unroll
        for (int u = 0; u < 8; ++u) {
          pl[ns][u] = bp[base + u * CC + lab];
          pb[ns][u] = bp[base + u * CC + (CC - 1)];
        }
      }
#pragma unroll
      for (int u = 0; u < 8; ++u) {
        const float PL  = pl[cs][u] + EPSF;
        const float PB  = pb[cs][u] + EPSF;
        const float a1p = wf_shr1_f(a1);                  // alpha[2i-1]
        const float na0 = (a0 + a1p) * PB;                // blank state 2i
        const float na2 = (a2 + a1) * PB;                 // state 2i+2
        const float na1 = fmaf(a1p, mskip, a1 + a0) * PL; // label state 2i+1
        a0 = na0; a1 = na1; a2 = na2;
      }
      if (cs) {  // rescale every 16 steps (decay ~2^-106 between rescales)
        float m = fmaxf(fmaxf(a0, a1), a2);
        m = dpp_max<0x111>(m);   // row_shr:1
        m = dpp_max<0x112>(m);   // row_shr:2
        m = dpp_max<0x114>(m);   // row_shr:4
        m = dpp_max<0x118>(m);   // row_shr:8
        m = dpp_max<0x142>(m);   // row_bcast:15
        m = dpp_max<0x143>(m);   // row_bcast:31  -> lane 63 = wave max
        const int mb = __builtin_amdgcn_readlane(__float_as_int(m), 63);
        const int k  = 223 - ((mb >> 23) & 0xFF);  // bring max to ~2^96
        scale += k;
        a0 = ldexpf(a0, k);
        a1 = ldexpf(a1, k);
        a2 = ldexpf(a2, k);
      }
    }

    // all ds_reads of buf[c&1] retired (results consumed) -> safe to overwrite
    if (c + 2 < NCH) {
      const char* g = src + (size_t)(c + 2) * CHUNK_BYTES + lane * 16;
      char* l = (char*)&buf[c & 1][0];
#pragma unroll
      for (int j = 0; j < 24; ++j) async16(l + j * 1024, g + j * 1024);
    }
  }

  if (lane == 63) {
    const float s = a1 + a2;  // alpha[127] + alpha[128] (scaled)
    out[b] = 0.693147180559945f * ((float)scale - log2f(s));
  }
}

extern "C" void kernel_launch(void* const* d_in, const int* in_sizes, int n_in,
                              void* d_out, int out_size, void* d_ws, size_t ws_size,
                              hipStream_t stream) {
  (void)in_sizes; (void)n_in; (void)d_ws; (void)ws_size; (void)out_size;
  const int*   y_true = (const int*)d_in[0];
  const float* y_pred = (const float*)d_in[1];
  float*       out    = (float*)d_out;
  ctc_fwd<<<BB, 64, 0, stream>>>(y_true, y_pred, out);
}